// Round 2
// baseline (1001.703 us; speedup 1.0000x reference)
//
#include <hip/hip_runtime.h>
#include <hip/hip_bf16.h>
#include <cstdint>
#include <cstddef>

#define T_TOK 4096
#define DDIM  1024
#define FDIM  4096
#define NEXP  8
#define MAXTILES 80
#define HROWS (2*T_TOK + 128)   // 8192 real rows + tile padding margin

typedef __attribute__((ext_vector_type(8))) short bf16x8;
typedef __attribute__((ext_vector_type(4))) float f32x4;

__device__ __forceinline__ unsigned short f2bf(float f) {
  union { float f; unsigned int u; } v; v.f = f;
  unsigned int u = v.u;
  return (unsigned short)((u + 0x7FFFu + ((u >> 16) & 1u)) >> 16);
}
__device__ __forceinline__ float bf2f(unsigned short b) {
  union { unsigned int u; float f; } v; v.u = ((unsigned int)b) << 16;
  return v.f;
}
__device__ __forceinline__ unsigned int pack2bf(float a, float b) {
  return (unsigned int)f2bf(a) | ((unsigned int)f2bf(b) << 16);
}
__device__ __forceinline__ void glds16(const void* gp, void* lp) {
  __builtin_amdgcn_global_load_lds(
      (const __attribute__((address_space(1))) unsigned int*)gp,
      (__attribute__((address_space(3))) unsigned int*)lp, 16, 0, 0);
}

// ---------------- zero y + counters ----------------
__global__ __launch_bounds__(256) void zero_k(float* __restrict__ y, int* __restrict__ cnt) {
  size_t i = (size_t)blockIdx.x * 256 + threadIdx.x;
  f32x4 z = 0.0f;
  ((f32x4*)y)[i] = z;                 // grid sized exactly: 4096*256*4 floats = 4,194,304
  if (i < NEXP) cnt[i] = 0;
}

// ---------------- x fp32 -> bf16 ----------------
__global__ __launch_bounds__(256) void cvt_x_k(const float* __restrict__ in, unsigned short* __restrict__ out) {
  size_t i = ((size_t)blockIdx.x * 256 + threadIdx.x) * 8;
  float4 a = *(const float4*)(in + i);
  float4 b = *(const float4*)(in + i + 4);
  uint4 o;
  o.x = pack2bf(a.x, a.y); o.y = pack2bf(a.z, a.w);
  o.z = pack2bf(b.x, b.y); o.w = pack2bf(b.z, b.w);
  *(uint4*)(out + i) = o;
}

// ------------- weight transpose + fp32->bf16: in [R][C] -> out [C][R] -------------
__global__ __launch_bounds__(256) void transpose_bf16_k(const float* __restrict__ in,
                                                        unsigned short* __restrict__ out,
                                                        int R, int C) {
  __shared__ float tile[64][65];
  const int t = threadIdx.x;
  const size_t mo = (size_t)blockIdx.z * (size_t)R * (size_t)C;
  const int r0 = blockIdx.y * 64, c0 = blockIdx.x * 64;
#pragma unroll
  for (int i = 0; i < 16; ++i) {
    int r = i * 4 + (t >> 6), c = t & 63;
    tile[r][c] = in[mo + (size_t)(r0 + r) * C + c0 + c];
  }
  __syncthreads();
#pragma unroll
  for (int i = 0; i < 2; ++i) {
    int G = i * 256 + t;
    int c = G >> 3, rg = (G & 7) * 8;
    uint4 o;
    o.x = pack2bf(tile[rg + 0][c], tile[rg + 1][c]);
    o.y = pack2bf(tile[rg + 2][c], tile[rg + 3][c]);
    o.z = pack2bf(tile[rg + 4][c], tile[rg + 5][c]);
    o.w = pack2bf(tile[rg + 6][c], tile[rg + 7][c]);
    *(uint4*)(out + mo + (size_t)(c0 + c) * R + r0 + rg) = o;
  }
}

// ---------------- router: logits, top-2, expert lists ----------------
__global__ __launch_bounds__(256) void router_k(const float* __restrict__ x,
                                                const float* __restrict__ gw,
                                                float* __restrict__ logits_out,
                                                int* __restrict__ cnt,
                                                int* __restrict__ lists,
                                                float* __restrict__ wgts) {
  const int wave = threadIdx.x >> 6, lane = threadIdx.x & 63;
  const int tok = blockIdx.x * 4 + wave;
  const float* xr = x + (size_t)tok * DDIM;
  float acc[NEXP];
#pragma unroll
  for (int e = 0; e < NEXP; ++e) acc[e] = 0.f;
#pragma unroll
  for (int i = 0; i < DDIM / 64; ++i) {
    int d = i * 64 + lane;
    float xv = xr[d];
    float4 g0 = *(const float4*)(gw + (size_t)d * NEXP);
    float4 g1 = *(const float4*)(gw + (size_t)d * NEXP + 4);
    acc[0] += xv * g0.x; acc[1] += xv * g0.y; acc[2] += xv * g0.z; acc[3] += xv * g0.w;
    acc[4] += xv * g1.x; acc[5] += xv * g1.y; acc[6] += xv * g1.z; acc[7] += xv * g1.w;
  }
#pragma unroll
  for (int m = 1; m < 64; m <<= 1)
#pragma unroll
    for (int e = 0; e < NEXP; ++e) acc[e] += __shfl_xor(acc[e], m, 64);
  if (lane == 0) {
#pragma unroll
    for (int e = 0; e < NEXP; ++e) logits_out[(size_t)tok * NEXP + e] = acc[e];
    int i0 = 0; float m0 = acc[0];
#pragma unroll
    for (int e = 1; e < NEXP; ++e) if (acc[e] > m0) { m0 = acc[e]; i0 = e; }
    int i1 = -1; float m1 = -3.4e38f;
#pragma unroll
    for (int e = 0; e < NEXP; ++e) if (e != i0 && acc[e] > m1) { m1 = acc[e]; i1 = e; }
    float w0 = 1.f / (1.f + expf(m1 - m0));   // = p0/(p0+p1) after softmax+renorm
    float w1 = 1.f - w0;
    int p0 = atomicAdd(&cnt[i0], 1); lists[i0 * T_TOK + p0] = tok; wgts[i0 * T_TOK + p0] = w0;
    int p1 = atomicAdd(&cnt[i1], 1); lists[i1 * T_TOK + p1] = tok; wgts[i1 * T_TOK + p1] = w1;
  }
}

// ---------------- tile map ----------------
__global__ void meta_k(const int* __restrict__ cnt, int* __restrict__ ebase,
                       int* __restrict__ tileE, int* __restrict__ tileR,
                       int* __restrict__ numTiles) {
  if (threadIdx.x == 0 && blockIdx.x == 0) {
    int b = 0, nt = 0;
    for (int e = 0; e < NEXP; ++e) {
      ebase[e] = b;
      int c = cnt[e]; b += c;
      for (int r = 0; r < c; r += 128) { tileE[nt] = e; tileR[nt] = r; ++nt; }
    }
    *numTiles = nt;
  }
}

// ---------------- grouped GEMM (m97 structure: 128x128 tile, BK=64) ----------------
// MODE 0: U = Xg @ W1t          (A gathered by token list, store bf16)
// MODE 1: V = Xg @ W3t, h = silu(U)*V stored IN PLACE over U (U aliases Obf)
// MODE 2: Y += (H @ W2t) * wgt  (A contiguous slots, fp32 atomicAdd scatter)
template <int MODE, int KTOT, int NTOT>
__global__ __launch_bounds__(256) void gemm_moe(
    const unsigned short* __restrict__ A,
    const unsigned short* __restrict__ B,
    const unsigned short* U,              // no restrict: aliases Obf in MODE 1
    unsigned short* Obf,
    float* __restrict__ Oy,
    const float* __restrict__ wgts,
    const int* __restrict__ lists,
    const int* __restrict__ cnt,
    const int* __restrict__ ebase,
    const int* __restrict__ tileE,
    const int* __restrict__ tileR,
    const int* __restrict__ numTiles) {
  const int tix = blockIdx.x;
  if (tix >= *numTiles) return;
  const int e = tileE[tix];
  const int r0 = tileR[tix];
  const int ce = cnt[e];
  const int nBase = blockIdx.y * 128;
  const int t = threadIdx.x;
  const int wave = t >> 6, lane = t & 63;

  __shared__ __align__(16) unsigned short As[128 * 64];
  __shared__ __align__(16) unsigned short Bs[128 * 64];

  // staging: 4 issues x 256 threads x 16B per buffer per K-step; LDS dest linear,
  // source column-granule XOR-swizzled so ds_read_b128 is 2-way (free) conflict
  const int cgs = (t & 7) ^ ((t >> 3) & 7);
  size_t aOff[4], bOff[4];
#pragma unroll
  for (int is = 0; is < 4; ++is) {
    int row = is * 32 + (t >> 3);
    size_t arow;
    if (MODE == 2) {
      arow = (size_t)(ebase[e] + r0 + row);          // padded rows read garbage; masked at store
    } else {
      int gr = r0 + row;
      arow = (size_t)lists[e * T_TOK + (gr < ce ? gr : 0)];
    }
    aOff[is] = (arow * (size_t)KTOT + (size_t)(cgs * 8)) * 2;
    bOff[is] = ((((size_t)e * NTOT) + nBase + row) * (size_t)KTOT + (size_t)(cgs * 8)) * 2;
  }

  f32x4 acc[4][4];
#pragma unroll
  for (int i = 0; i < 4; ++i)
#pragma unroll
    for (int j = 0; j < 4; ++j) acc[i][j] = 0.0f;

  const int wm = wave >> 1, wn = wave & 1;

  for (int k0 = 0; k0 < KTOT; k0 += 64) {
#pragma unroll
    for (int is = 0; is < 4; ++is) {
      glds16((const char*)A + aOff[is] + (size_t)k0 * 2, (char*)As + is * 4096 + wave * 1024);
      glds16((const char*)B + bOff[is] + (size_t)k0 * 2, (char*)Bs + is * 4096 + wave * 1024);
    }
    __syncthreads();
#pragma unroll
    for (int kk = 0; kk < 2; ++kk) {
      bf16x8 af[4], bfr[4];
#pragma unroll
      for (int fm = 0; fm < 4; ++fm) {
        int row = wm * 64 + fm * 16 + (lane & 15);
        int g = (kk * 4 + (lane >> 4)) ^ (row & 7);
        af[fm] = *(const bf16x8*)((const char*)As + row * 128 + g * 16);
      }
#pragma unroll
      for (int fn = 0; fn < 4; ++fn) {
        int row = wn * 64 + fn * 16 + (lane & 15);
        int g = (kk * 4 + (lane >> 4)) ^ (row & 7);
        bfr[fn] = *(const bf16x8*)((const char*)Bs + row * 128 + g * 16);
      }
#pragma unroll
      for (int fm = 0; fm < 4; ++fm)
#pragma unroll
        for (int fn = 0; fn < 4; ++fn)
          acc[fm][fn] = __builtin_amdgcn_mfma_f32_16x16x32_bf16(af[fm], bfr[fn], acc[fm][fn], 0, 0, 0);
    }
    __syncthreads();
  }

  // epilogue; C/D frag map: row = (lane>>4)*4 + j, col = lane&15
  const int eb = (MODE == 2) ? 0 : ebase[e];
#pragma unroll
  for (int fm = 0; fm < 4; ++fm) {
#pragma unroll
    for (int j = 0; j < 4; ++j) {
      int lrow = wm * 64 + fm * 16 + (lane >> 4) * 4 + j;
      int gr = r0 + lrow;
      if (gr >= ce) continue;
      if (MODE == 2) {
        int tok = lists[e * T_TOK + gr];
        float wv = wgts[e * T_TOK + gr];
        float* yrow = Oy + (size_t)tok * DDIM + nBase + wn * 64 + (lane & 15);
#pragma unroll
        for (int fn = 0; fn < 4; ++fn) atomicAdd(yrow + fn * 16, acc[fm][fn][j] * wv);
      } else {
        size_t off = (size_t)(eb + gr) * NTOT + nBase + wn * 64 + (lane & 15);
#pragma unroll
        for (int fn = 0; fn < 4; ++fn) {
          float v = acc[fm][fn][j];
          if (MODE == 1) {
            float uu = bf2f(U[off + fn * 16]);
            v = (uu / (1.f + __expf(-uu))) * v;   // silu(u) * v
          }
          Obf[off + fn * 16] = f2bf(v);
        }
      }
    }
  }
}

extern "C" void kernel_launch(void* const* d_in, const int* in_sizes, int n_in,
                              void* d_out, int out_size, void* d_ws, size_t ws_size,
                              hipStream_t stream) {
  const float* x  = (const float*)d_in[0];
  const float* gw = (const float*)d_in[1];
  const float* w1 = (const float*)d_in[2];   // dict order: x, gate_w, w1, w3, w2
  const float* w3 = (const float*)d_in[3];
  const float* w2 = (const float*)d_in[4];
  float* y = (float*)d_out;
  float* logits = y + (size_t)T_TOK * DDIM;

  char* ws = (char*)d_ws;
  size_t o = 0;
  auto alloc = [&](size_t bytes) {
    char* p = ws + o;
    o = (o + bytes + 255) & ~(size_t)255;
    return p;
  };
  unsigned short* xb  = (unsigned short*)alloc((size_t)T_TOK * DDIM * 2);
  unsigned short* w1t = (unsigned short*)alloc((size_t)NEXP * FDIM * DDIM * 2);  // [E][F][D]
  unsigned short* w3t = (unsigned short*)alloc((size_t)NEXP * FDIM * DDIM * 2);  // [E][F][D]
  unsigned short* w2t = (unsigned short*)alloc((size_t)NEXP * DDIM * FDIM * 2);  // [E][D][F]
  unsigned short* ub  = (unsigned short*)alloc((size_t)HROWS * FDIM * 2);        // u, then h in-place
  int*   lists = (int*)alloc((size_t)NEXP * T_TOK * 4);
  float* wgts  = (float*)alloc((size_t)NEXP * T_TOK * 4);
  int* cnt      = (int*)alloc(64);
  int* ebase    = (int*)alloc(64);
  int* tileE    = (int*)alloc(MAXTILES * 4);
  int* tileR    = (int*)alloc(MAXTILES * 4);
  int* numTiles = (int*)alloc(64);

  zero_k<<<4096, 256, 0, stream>>>(y, cnt);
  cvt_x_k<<<(T_TOK * DDIM / 8) / 256, 256, 0, stream>>>(x, xb);
  transpose_bf16_k<<<dim3(FDIM / 64, DDIM / 64, NEXP), 256, 0, stream>>>(w1, w1t, DDIM, FDIM);
  transpose_bf16_k<<<dim3(FDIM / 64, DDIM / 64, NEXP), 256, 0, stream>>>(w3, w3t, DDIM, FDIM);
  transpose_bf16_k<<<dim3(DDIM / 64, FDIM / 64, NEXP), 256, 0, stream>>>(w2, w2t, FDIM, DDIM);
  router_k<<<T_TOK / 4, 256, 0, stream>>>(x, gw, logits, cnt, lists, wgts);
  meta_k<<<1, 64, 0, stream>>>(cnt, ebase, tileE, tileR, numTiles);

  gemm_moe<0, DDIM, FDIM><<<dim3(MAXTILES, FDIM / 128), 256, 0, stream>>>(
      xb, w1t, nullptr, ub, nullptr, nullptr, lists, cnt, ebase, tileE, tileR, numTiles);
  gemm_moe<1, DDIM, FDIM><<<dim3(MAXTILES, FDIM / 128), 256, 0, stream>>>(
      xb, w3t, ub, ub, nullptr, nullptr, lists, cnt, ebase, tileE, tileR, numTiles);
  gemm_moe<2, FDIM, DDIM><<<dim3(MAXTILES, DDIM / 128), 256, 0, stream>>>(
      ub, w2t, nullptr, nullptr, y, wgts, lists, cnt, ebase, tileE, tileR, numTiles);
}

// Round 3
// 942.259 us; speedup vs baseline: 1.0631x; 1.0631x over previous
//
#include <hip/hip_runtime.h>
#include <hip/hip_bf16.h>
#include <cstdint>
#include <cstddef>

#define T_TOK 4096
#define DDIM  1024
#define FDIM  4096
#define NEXP  8
#define MAXTILES 80
#define HROWS (2*T_TOK + 128)

typedef __attribute__((ext_vector_type(8))) short bf16x8;
typedef __attribute__((ext_vector_type(4))) float f32x4;

__device__ __forceinline__ unsigned short f2bf(float f) {
  union { float f; unsigned int u; } v; v.f = f;
  unsigned int u = v.u;
  return (unsigned short)((u + 0x7FFFu + ((u >> 16) & 1u)) >> 16);
}
__device__ __forceinline__ unsigned int pack2bf(float a, float b) {
  return (unsigned int)f2bf(a) | ((unsigned int)f2bf(b) << 16);
}
__device__ __forceinline__ void glds16(const void* gp, void* lp) {
  __builtin_amdgcn_global_load_lds(
      (const __attribute__((address_space(1))) unsigned int*)gp,
      (__attribute__((address_space(3))) unsigned int*)lp, 16, 0, 0);
}

// ---------------- zero y + counters ----------------
__global__ __launch_bounds__(256) void zero_k(float* __restrict__ y, int* __restrict__ cnt) {
  size_t i = (size_t)blockIdx.x * 256 + threadIdx.x;
  f32x4 z = 0.0f;
  ((f32x4*)y)[i] = z;
  if (i < NEXP) cnt[i] = 0;
}

// ------------- weight transpose + fp32->bf16: in [R][C] -> out [C][R] -------------
__global__ __launch_bounds__(256) void transpose_bf16_k(const float* __restrict__ in,
                                                        unsigned short* __restrict__ out,
                                                        int R, int C) {
  __shared__ float tile[64][65];
  const int t = threadIdx.x;
  const size_t mo = (size_t)blockIdx.z * (size_t)R * (size_t)C;
  const int r0 = blockIdx.y * 64, c0 = blockIdx.x * 64;
#pragma unroll
  for (int i = 0; i < 4; ++i) {
    int r = i * 16 + (t >> 4), c4 = (t & 15) * 4;
    float4 v = *(const float4*)&in[mo + (size_t)(r0 + r) * C + c0 + c4];
    tile[r][c4 + 0] = v.x; tile[r][c4 + 1] = v.y;
    tile[r][c4 + 2] = v.z; tile[r][c4 + 3] = v.w;
  }
  __syncthreads();
#pragma unroll
  for (int i = 0; i < 2; ++i) {
    int G = i * 256 + t;
    int c = G >> 3, rg = (G & 7) * 8;
    uint4 o;
    o.x = pack2bf(tile[rg + 0][c], tile[rg + 1][c]);
    o.y = pack2bf(tile[rg + 2][c], tile[rg + 3][c]);
    o.z = pack2bf(tile[rg + 4][c], tile[rg + 5][c]);
    o.w = pack2bf(tile[rg + 6][c], tile[rg + 7][c]);
    *(uint4*)(out + mo + (size_t)(c0 + c) * R + r0 + rg) = o;
  }
}

// ---------------- router: logits, top-2, expert lists, x->bf16 ----------------
__global__ __launch_bounds__(256) void router_k(const float* __restrict__ x,
                                                const float* __restrict__ gw,
                                                float* __restrict__ logits_out,
                                                unsigned short* __restrict__ xb,
                                                int* __restrict__ cnt,
                                                int* __restrict__ lists,
                                                float* __restrict__ wgts) {
  const int wave = threadIdx.x >> 6, lane = threadIdx.x & 63;
  const int tok = blockIdx.x * 4 + wave;
  const float* xr = x + (size_t)tok * DDIM;
  unsigned short* xbr = xb + (size_t)tok * DDIM;
  float acc[NEXP];
#pragma unroll
  for (int e = 0; e < NEXP; ++e) acc[e] = 0.f;
#pragma unroll
  for (int i = 0; i < DDIM / 64; ++i) {
    int d = i * 64 + lane;
    float xv = xr[d];
    xbr[d] = f2bf(xv);
    float4 g0 = *(const float4*)(gw + (size_t)d * NEXP);
    float4 g1 = *(const float4*)(gw + (size_t)d * NEXP + 4);
    acc[0] += xv * g0.x; acc[1] += xv * g0.y; acc[2] += xv * g0.z; acc[3] += xv * g0.w;
    acc[4] += xv * g1.x; acc[5] += xv * g1.y; acc[6] += xv * g1.z; acc[7] += xv * g1.w;
  }
#pragma unroll
  for (int m = 1; m < 64; m <<= 1)
#pragma unroll
    for (int e = 0; e < NEXP; ++e) acc[e] += __shfl_xor(acc[e], m, 64);
  if (lane == 0) {
#pragma unroll
    for (int e = 0; e < NEXP; ++e) logits_out[(size_t)tok * NEXP + e] = acc[e];
    int i0 = 0; float m0 = acc[0];
#pragma unroll
    for (int e = 1; e < NEXP; ++e) if (acc[e] > m0) { m0 = acc[e]; i0 = e; }
    int i1 = -1; float m1 = -3.4e38f;
#pragma unroll
    for (int e = 0; e < NEXP; ++e) if (e != i0 && acc[e] > m1) { m1 = acc[e]; i1 = e; }
    float w0 = 1.f / (1.f + expf(m1 - m0));
    float w1 = 1.f - w0;
    int p0 = atomicAdd(&cnt[i0], 1); lists[i0 * T_TOK + p0] = tok; wgts[i0 * T_TOK + p0] = w0;
    int p1 = atomicAdd(&cnt[i1], 1); lists[i1 * T_TOK + p1] = tok; wgts[i1 * T_TOK + p1] = w1;
  }
}

// ---------------- tile map (128-row tiles, shared by both GEMMs) ----------------
__global__ void meta_k(const int* __restrict__ cnt, int* __restrict__ ebase,
                       int* __restrict__ tileE, int* __restrict__ tileR,
                       int* __restrict__ numTiles) {
  if (threadIdx.x == 0 && blockIdx.x == 0) {
    int b = 0, nt = 0;
    for (int e = 0; e < NEXP; ++e) {
      ebase[e] = b;
      int c = cnt[e]; b += c;
      for (int r = 0; r < c; r += 128) { tileE[nt] = e; tileR[nt] = r; ++nt; }
    }
    *numTiles = nt;
  }
}

// ======= fused GEMM1+GEMM3: per block 128 rows x (64 W1-cols + 64 W3-cols), BK=64 =======
// 2-phase double-buffered: stage(next) -> compute(cur) -> ONE __syncthreads per K-step.
// h = silu(x@w1) * (x@w3) written bf16 to H slots.
__global__ __launch_bounds__(256) void gemm01_k(
    const unsigned short* __restrict__ A,    // xb [T][D]
    const unsigned short* __restrict__ B1,   // w1t [E][F][D]
    const unsigned short* __restrict__ B3,   // w3t [E][F][D]
    unsigned short* __restrict__ H,          // [HROWS][F]
    const int* __restrict__ lists, const int* __restrict__ cnt,
    const int* __restrict__ ebase,
    const int* __restrict__ tileE, const int* __restrict__ tileR,
    const int* __restrict__ numTiles) {
  const int tix = blockIdx.x;
  if (tix >= *numTiles) return;
  const int e = tileE[tix], r0 = tileR[tix], ce = cnt[e];
  const int nBase = blockIdx.y * 64;
  const int t = threadIdx.x, wave = t >> 6, lane = t & 63;

  __shared__ __align__(16) unsigned short As[2][128 * 64];
  __shared__ __align__(16) unsigned short Bs[2][128 * 64];  // rows 0..63 = W1, 64..127 = W3

  const int cgs = (t & 7) ^ ((t >> 3) & 7);
  size_t aOff[4], bOff[4];
  const unsigned short* bBase[4];
#pragma unroll
  for (int is = 0; is < 4; ++is) {
    int row = is * 32 + (t >> 3);
    int gr = r0 + row;
    size_t arow = (size_t)lists[e * T_TOK + (gr < ce ? gr : 0)];
    aOff[is] = (arow * DDIM + (size_t)(cgs * 8)) * 2;
    int brow = row;                       // 0..127
    const unsigned short* src = (brow < 64) ? B1 : B3;
    int n = nBase + (brow & 63);
    bBase[is] = src;
    bOff[is] = (((size_t)e * FDIM + n) * DDIM + (size_t)(cgs * 8)) * 2;
  }

  f32x4 accU[4][2], accV[4][2];
#pragma unroll
  for (int i = 0; i < 4; ++i)
#pragma unroll
    for (int j = 0; j < 2; ++j) { accU[i][j] = 0.0f; accV[i][j] = 0.0f; }

  const int wm = wave >> 1, wn = wave & 1;

#define STAGE01(buf, k0)                                                              \
  {                                                                                   \
    _Pragma("unroll") for (int is = 0; is < 4; ++is) {                                \
      glds16((const char*)A + aOff[is] + (size_t)(k0) * 2,                            \
             (char*)&As[buf][0] + is * 4096 + wave * 1024);                           \
      glds16((const char*)bBase[is] + bOff[is] + (size_t)(k0) * 2,                    \
             (char*)&Bs[buf][0] + is * 4096 + wave * 1024);                           \
    }                                                                                 \
  }

  STAGE01(0, 0);
  __syncthreads();
  int cur = 0;
  for (int ks = 0; ks < DDIM / 64; ++ks) {
    if (ks < DDIM / 64 - 1) STAGE01(cur ^ 1, (ks + 1) * 64);
#pragma unroll
    for (int kk = 0; kk < 2; ++kk) {
      bf16x8 af[4], bu[2], bv[2];
#pragma unroll
      for (int fm = 0; fm < 4; ++fm) {
        int row = wm * 64 + fm * 16 + (lane & 15);
        int g = (kk * 4 + (lane >> 4)) ^ (row & 7);
        af[fm] = *(const bf16x8*)((const char*)&As[cur][0] + row * 128 + g * 16);
      }
#pragma unroll
      for (int fn = 0; fn < 2; ++fn) {
        int row = wn * 32 + fn * 16 + (lane & 15);
        int g = (kk * 4 + (lane >> 4)) ^ (row & 7);
        bu[fn] = *(const bf16x8*)((const char*)&Bs[cur][0] + row * 128 + g * 16);
        bv[fn] = *(const bf16x8*)((const char*)&Bs[cur][0] + (row + 64) * 128 + g * 16);
      }
#pragma unroll
      for (int fm = 0; fm < 4; ++fm)
#pragma unroll
        for (int fn = 0; fn < 2; ++fn) {
          accU[fm][fn] = __builtin_amdgcn_mfma_f32_16x16x32_bf16(af[fm], bu[fn], accU[fm][fn], 0, 0, 0);
          accV[fm][fn] = __builtin_amdgcn_mfma_f32_16x16x32_bf16(af[fm], bv[fn], accV[fm][fn], 0, 0, 0);
        }
    }
    __syncthreads();
    cur ^= 1;
  }
#undef STAGE01

  const int eb = ebase[e];
#pragma unroll
  for (int fm = 0; fm < 4; ++fm) {
#pragma unroll
    for (int j = 0; j < 4; ++j) {
      int lrow = wm * 64 + fm * 16 + (lane >> 4) * 4 + j;
      int gr = r0 + lrow;
      if (gr >= ce) continue;
      size_t base = (size_t)(eb + gr) * FDIM + nBase + wn * 32 + (lane & 15);
#pragma unroll
      for (int fn = 0; fn < 2; ++fn) {
        float u = accU[fm][fn][j], v = accV[fm][fn][j];
        float h = (u / (1.f + __expf(-u))) * v;
        H[base + fn * 16] = f2bf(h);
      }
    }
  }
}

// ======= GEMM2: Y += (H @ W2t) * wgt, 128x128, BK=64, 2-phase double-buffered =======
__global__ __launch_bounds__(256) void gemm2_k(
    const unsigned short* __restrict__ A,    // H [HROWS][F]
    const unsigned short* __restrict__ B,    // w2t [E][D][F]
    float* __restrict__ Oy,
    const float* __restrict__ wgts, const int* __restrict__ lists,
    const int* __restrict__ cnt, const int* __restrict__ ebase,
    const int* __restrict__ tileE, const int* __restrict__ tileR,
    const int* __restrict__ numTiles) {
  const int tix = blockIdx.x;
  if (tix >= *numTiles) return;
  const int e = tileE[tix], r0 = tileR[tix], ce = cnt[e];
  const int nBase = blockIdx.y * 128;
  const int t = threadIdx.x, wave = t >> 6, lane = t & 63;

  __shared__ __align__(16) unsigned short As[2][128 * 64];
  __shared__ __align__(16) unsigned short Bs[2][128 * 64];

  const int cgs = (t & 7) ^ ((t >> 3) & 7);
  size_t aOff[4], bOff[4];
#pragma unroll
  for (int is = 0; is < 4; ++is) {
    int row = is * 32 + (t >> 3);
    size_t arow = (size_t)(ebase[e] + r0 + row);            // pad rows read garbage; masked at store
    aOff[is] = (arow * FDIM + (size_t)(cgs * 8)) * 2;
    bOff[is] = (((size_t)e * DDIM + nBase + row) * FDIM + (size_t)(cgs * 8)) * 2;
  }

  f32x4 acc[4][4];
#pragma unroll
  for (int i = 0; i < 4; ++i)
#pragma unroll
    for (int j = 0; j < 4; ++j) acc[i][j] = 0.0f;

  const int wm = wave >> 1, wn = wave & 1;

#define STAGE2(buf, k0)                                                               \
  {                                                                                   \
    _Pragma("unroll") for (int is = 0; is < 4; ++is) {                                \
      glds16((const char*)A + aOff[is] + (size_t)(k0) * 2,                            \
             (char*)&As[buf][0] + is * 4096 + wave * 1024);                           \
      glds16((const char*)B + bOff[is] + (size_t)(k0) * 2,                            \
             (char*)&Bs[buf][0] + is * 4096 + wave * 1024);                           \
    }                                                                                 \
  }

  STAGE2(0, 0);
  __syncthreads();
  int cur = 0;
  for (int ks = 0; ks < FDIM / 64; ++ks) {
    if (ks < FDIM / 64 - 1) STAGE2(cur ^ 1, (ks + 1) * 64);
#pragma unroll
    for (int kk = 0; kk < 2; ++kk) {
      bf16x8 af[4], bfr[4];
#pragma unroll
      for (int fm = 0; fm < 4; ++fm) {
        int row = wm * 64 + fm * 16 + (lane & 15);
        int g = (kk * 4 + (lane >> 4)) ^ (row & 7);
        af[fm] = *(const bf16x8*)((const char*)&As[cur][0] + row * 128 + g * 16);
      }
#pragma unroll
      for (int fn = 0; fn < 4; ++fn) {
        int row = wn * 64 + fn * 16 + (lane & 15);
        int g = (kk * 4 + (lane >> 4)) ^ (row & 7);
        bfr[fn] = *(const bf16x8*)((const char*)&Bs[cur][0] + row * 128 + g * 16);
      }
#pragma unroll
      for (int fm = 0; fm < 4; ++fm)
#pragma unroll
        for (int fn = 0; fn < 4; ++fn)
          acc[fm][fn] = __builtin_amdgcn_mfma_f32_16x16x32_bf16(af[fm], bfr[fn], acc[fm][fn], 0, 0, 0);
    }
    __syncthreads();
    cur ^= 1;
  }
#undef STAGE2

#pragma unroll
  for (int fm = 0; fm < 4; ++fm) {
#pragma unroll
    for (int j = 0; j < 4; ++j) {
      int lrow = wm * 64 + fm * 16 + (lane >> 4) * 4 + j;
      int gr = r0 + lrow;
      if (gr >= ce) continue;
      int tok = lists[e * T_TOK + gr];
      float wv = wgts[e * T_TOK + gr];
      float* yrow = Oy + (size_t)tok * DDIM + nBase + wn * 64 + (lane & 15);
#pragma unroll
      for (int fn = 0; fn < 4; ++fn) atomicAdd(yrow + fn * 16, acc[fm][fn][j] * wv);
    }
  }
}

extern "C" void kernel_launch(void* const* d_in, const int* in_sizes, int n_in,
                              void* d_out, int out_size, void* d_ws, size_t ws_size,
                              hipStream_t stream) {
  const float* x  = (const float*)d_in[0];
  const float* gw = (const float*)d_in[1];
  const float* w1 = (const float*)d_in[2];   // dict order: x, gate_w, w1, w3, w2
  const float* w3 = (const float*)d_in[3];
  const float* w2 = (const float*)d_in[4];
  float* y = (float*)d_out;
  float* logits = y + (size_t)T_TOK * DDIM;

  char* ws = (char*)d_ws;
  size_t o = 0;
  auto alloc = [&](size_t bytes) {
    char* p = ws + o;
    o = (o + bytes + 255) & ~(size_t)255;
    return p;
  };
  unsigned short* xb  = (unsigned short*)alloc((size_t)T_TOK * DDIM * 2);
  unsigned short* w1t = (unsigned short*)alloc((size_t)NEXP * FDIM * DDIM * 2);  // [E][F][D]
  unsigned short* w3t = (unsigned short*)alloc((size_t)NEXP * FDIM * DDIM * 2);  // [E][F][D]
  unsigned short* w2t = (unsigned short*)alloc((size_t)NEXP * DDIM * FDIM * 2);  // [E][D][F]
  unsigned short* hb  = (unsigned short*)alloc((size_t)HROWS * FDIM * 2);        // h slots
  int*   lists = (int*)alloc((size_t)NEXP * T_TOK * 4);
  float* wgts  = (float*)alloc((size_t)NEXP * T_TOK * 4);
  int* cnt      = (int*)alloc(64);
  int* ebase    = (int*)alloc(64);
  int* tileE    = (int*)alloc(MAXTILES * 4);
  int* tileR    = (int*)alloc(MAXTILES * 4);
  int* numTiles = (int*)alloc(64);

  zero_k<<<4096, 256, 0, stream>>>(y, cnt);
  transpose_bf16_k<<<dim3(FDIM / 64, DDIM / 64, NEXP), 256, 0, stream>>>(w1, w1t, DDIM, FDIM);
  transpose_bf16_k<<<dim3(FDIM / 64, DDIM / 64, NEXP), 256, 0, stream>>>(w3, w3t, DDIM, FDIM);
  transpose_bf16_k<<<dim3(DDIM / 64, FDIM / 64, NEXP), 256, 0, stream>>>(w2, w2t, FDIM, DDIM);
  router_k<<<T_TOK / 4, 256, 0, stream>>>(x, gw, logits, xb, cnt, lists, wgts);
  meta_k<<<1, 64, 0, stream>>>(cnt, ebase, tileE, tileR, numTiles);

  gemm01_k<<<dim3(MAXTILES, FDIM / 64), 256, 0, stream>>>(
      xb, w1t, w3t, hb, lists, cnt, ebase, tileE, tileR, numTiles);
  gemm2_k<<<dim3(MAXTILES, DDIM / 128), 256, 0, stream>>>(
      hb, w2t, y, wgts, lists, cnt, ebase, tileE, tileR, numTiles);
}

// Round 5
// 931.150 us; speedup vs baseline: 1.0758x; 1.0119x over previous
//
#include <hip/hip_runtime.h>
#include <hip/hip_bf16.h>
#include <cstdint>
#include <cstddef>

#define T_TOK 4096
#define DDIM  1024
#define FDIM  4096
#define NEXP  8
#define MAXTILES 80
#define HROWS (2*T_TOK + 128)

typedef __attribute__((ext_vector_type(8))) short bf16x8;
typedef __attribute__((ext_vector_type(4))) float f32x4;

__device__ __forceinline__ unsigned short f2bf(float f) {
  union { float f; unsigned int u; } v; v.f = f;
  unsigned int u = v.u;
  return (unsigned short)((u + 0x7FFFu + ((u >> 16) & 1u)) >> 16);
}
__device__ __forceinline__ unsigned int pack2bf(float a, float b) {
  return (unsigned int)f2bf(a) | ((unsigned int)f2bf(b) << 16);
}
__device__ __forceinline__ void glds16(const void* gp, void* lp) {
  __builtin_amdgcn_global_load_lds(
      (const __attribute__((address_space(1))) unsigned int*)gp,
      (__attribute__((address_space(3))) unsigned int*)lp, 16, 0, 0);
}

// ---------------- zero y + counters ----------------
__global__ __launch_bounds__(256) void zero_k(float* __restrict__ y, int* __restrict__ cnt) {
  size_t i = (size_t)blockIdx.x * 256 + threadIdx.x;
  f32x4 z = 0.0f;
  ((f32x4*)y)[i] = z;
  if (i < NEXP) cnt[i] = 0;
}

// ------------- all 3 weight transposes fused: fp32 [R][C] -> bf16 [C][R] -------------
__global__ __launch_bounds__(256) void transpose_all_k(const float* __restrict__ w1,
                                                       const float* __restrict__ w3,
                                                       const float* __restrict__ w2,
                                                       unsigned short* __restrict__ w1t,
                                                       unsigned short* __restrict__ w3t,
                                                       unsigned short* __restrict__ w2t) {
  __shared__ float tile[64][65];
  const int t = threadIdx.x;
  const int z = blockIdx.z, m = z >> 3, e = z & 7;
  const float* in; unsigned short* out; int R, C;
  if (m == 0)      { in = w1; out = w1t; R = DDIM; C = FDIM; }
  else if (m == 1) { in = w3; out = w3t; R = DDIM; C = FDIM; }
  else             { in = w2; out = w2t; R = FDIM; C = DDIM; }
  const size_t mo = (size_t)e * (size_t)R * (size_t)C;
  const int ntx = C >> 6;
  const int c0 = (blockIdx.x % ntx) * 64, r0 = (blockIdx.x / ntx) * 64;
#pragma unroll
  for (int i = 0; i < 4; ++i) {
    int r = i * 16 + (t >> 4), c4 = (t & 15) * 4;
    float4 v = *(const float4*)&in[mo + (size_t)(r0 + r) * C + c0 + c4];
    tile[r][c4 + 0] = v.x; tile[r][c4 + 1] = v.y;
    tile[r][c4 + 2] = v.z; tile[r][c4 + 3] = v.w;
  }
  __syncthreads();
#pragma unroll
  for (int i = 0; i < 2; ++i) {
    int G = i * 256 + t;
    int c = G >> 3, rg = (G & 7) * 8;
    uint4 o;
    o.x = pack2bf(tile[rg + 0][c], tile[rg + 1][c]);
    o.y = pack2bf(tile[rg + 2][c], tile[rg + 3][c]);
    o.z = pack2bf(tile[rg + 4][c], tile[rg + 5][c]);
    o.w = pack2bf(tile[rg + 6][c], tile[rg + 7][c]);
    *(uint4*)(out + mo + (size_t)(c0 + c) * R + r0 + rg) = o;
  }
}

// ---------------- router: logits, top-2, expert lists, x->bf16 ----------------
__global__ __launch_bounds__(256) void router_k(const float* __restrict__ x,
                                                const float* __restrict__ gw,
                                                float* __restrict__ logits_out,
                                                unsigned short* __restrict__ xb,
                                                int* __restrict__ cnt,
                                                int* __restrict__ lists,
                                                float* __restrict__ wgts) {
  const int wave = threadIdx.x >> 6, lane = threadIdx.x & 63;
  const int tok = blockIdx.x * 4 + wave;
  const float* xr = x + (size_t)tok * DDIM;
  unsigned short* xbr = xb + (size_t)tok * DDIM;
  float acc[NEXP];
#pragma unroll
  for (int e = 0; e < NEXP; ++e) acc[e] = 0.f;
#pragma unroll
  for (int i = 0; i < DDIM / 64; ++i) {
    int d = i * 64 + lane;
    float xv = xr[d];
    xbr[d] = f2bf(xv);
    float4 g0 = *(const float4*)(gw + (size_t)d * NEXP);
    float4 g1 = *(const float4*)(gw + (size_t)d * NEXP + 4);
    acc[0] += xv * g0.x; acc[1] += xv * g0.y; acc[2] += xv * g0.z; acc[3] += xv * g0.w;
    acc[4] += xv * g1.x; acc[5] += xv * g1.y; acc[6] += xv * g1.z; acc[7] += xv * g1.w;
  }
#pragma unroll
  for (int m = 1; m < 64; m <<= 1)
#pragma unroll
    for (int e = 0; e < NEXP; ++e) acc[e] += __shfl_xor(acc[e], m, 64);
  if (lane == 0) {
#pragma unroll
    for (int e = 0; e < NEXP; ++e) logits_out[(size_t)tok * NEXP + e] = acc[e];
    int i0 = 0; float m0 = acc[0];
#pragma unroll
    for (int e = 1; e < NEXP; ++e) if (acc[e] > m0) { m0 = acc[e]; i0 = e; }
    int i1 = -1; float m1 = -3.4e38f;
#pragma unroll
    for (int e = 0; e < NEXP; ++e) if (e != i0 && acc[e] > m1) { m1 = acc[e]; i1 = e; }
    float w0 = 1.f / (1.f + expf(m1 - m0));
    float w1 = 1.f - w0;
    int p0 = atomicAdd(&cnt[i0], 1); lists[i0 * T_TOK + p0] = tok; wgts[i0 * T_TOK + p0] = w0;
    int p1 = atomicAdd(&cnt[i1], 1); lists[i1 * T_TOK + p1] = tok; wgts[i1 * T_TOK + p1] = w1;
  }
}

// ---------------- tile map ----------------
__global__ void meta_k(const int* __restrict__ cnt, int* __restrict__ ebase,
                       int* __restrict__ tileE, int* __restrict__ tileR,
                       int* __restrict__ numTiles) {
  if (threadIdx.x == 0 && blockIdx.x == 0) {
    int b = 0, nt = 0;
    for (int e = 0; e < NEXP; ++e) {
      ebase[e] = b;
      int c = cnt[e]; b += c;
      for (int r = 0; r < c; r += 128) { tileE[nt] = e; tileR[nt] = r; ++nt; }
    }
    *numTiles = nt;
  }
}

// ======= fused GEMM1+GEMM3: 128 rows x (64 W1-cols + 64 W3-cols), BK=64, 2-phase =======
// XCD-panel swizzle: flat grid 5120 = 8 XCD x 8 panels x 80 tiles; each XCD owns 8
// contiguous N-panels, iterating tiles fastest -> panel weights stay in its L2.
__global__ __launch_bounds__(256) void gemm01_k(
    const unsigned short* __restrict__ A,    // xb [T][D]
    const unsigned short* __restrict__ B1,   // w1t [E][F][D]
    const unsigned short* __restrict__ B3,   // w3t [E][F][D]
    unsigned short* __restrict__ H,          // [HROWS][F]
    const int* __restrict__ lists, const int* __restrict__ cnt,
    const int* __restrict__ ebase,
    const int* __restrict__ tileE, const int* __restrict__ tileR,
    const int* __restrict__ numTiles) {
  const int bid = blockIdx.x;
  const int xcd = bid & 7;
  const int j = bid >> 3;                  // 0..639 within XCD
  const int tix = j % MAXTILES;            // tiles fastest
  const int panel = xcd * 8 + j / MAXTILES;
  if (tix >= *numTiles) return;
  const int e = tileE[tix], r0 = tileR[tix], ce = cnt[e];
  const int nBase = panel * 64;
  const int t = threadIdx.x, wave = t >> 6, lane = t & 63;

  __shared__ __align__(16) unsigned short As[2][128 * 64];
  __shared__ __align__(16) unsigned short Bs[2][128 * 64];  // rows 0..63 = W1, 64..127 = W3

  const int cgs = (t & 7) ^ ((t >> 3) & 7);
  size_t aOff[4], bOff[4];
  const unsigned short* bBase[4];
#pragma unroll
  for (int is = 0; is < 4; ++is) {
    int row = is * 32 + (t >> 3);
    int gr = r0 + row;
    size_t arow = (size_t)lists[e * T_TOK + (gr < ce ? gr : 0)];
    aOff[is] = (arow * DDIM + (size_t)(cgs * 8)) * 2;
    const unsigned short* src = (row < 64) ? B1 : B3;
    int n = nBase + (row & 63);
    bBase[is] = src;
    bOff[is] = (((size_t)e * FDIM + n) * DDIM + (size_t)(cgs * 8)) * 2;
  }

  f32x4 accU[4][2], accV[4][2];
#pragma unroll
  for (int i = 0; i < 4; ++i)
#pragma unroll
    for (int j2 = 0; j2 < 2; ++j2) { accU[i][j2] = 0.0f; accV[i][j2] = 0.0f; }

  const int wm = wave >> 1, wn = wave & 1;

#define STAGE01(buf, k0)                                                              \
  {                                                                                   \
    _Pragma("unroll") for (int is = 0; is < 4; ++is) {                                \
      glds16((const char*)A + aOff[is] + (size_t)(k0) * 2,                            \
             (char*)&As[buf][0] + is * 4096 + wave * 1024);                           \
      glds16((const char*)bBase[is] + bOff[is] + (size_t)(k0) * 2,                    \
             (char*)&Bs[buf][0] + is * 4096 + wave * 1024);                           \
    }                                                                                 \
  }

  STAGE01(0, 0);
  __syncthreads();
  int cur = 0;
  for (int ks = 0; ks < DDIM / 64; ++ks) {
    if (ks < DDIM / 64 - 1) STAGE01(cur ^ 1, (ks + 1) * 64);
#pragma unroll
    for (int kk = 0; kk < 2; ++kk) {
      bf16x8 af[4], bu[2], bv[2];
#pragma unroll
      for (int fm = 0; fm < 4; ++fm) {
        int row = wm * 64 + fm * 16 + (lane & 15);
        int g = (kk * 4 + (lane >> 4)) ^ (row & 7);
        af[fm] = *(const bf16x8*)((const char*)&As[cur][0] + row * 128 + g * 16);
      }
#pragma unroll
      for (int fn = 0; fn < 2; ++fn) {
        int row = wn * 32 + fn * 16 + (lane & 15);
        int g = (kk * 4 + (lane >> 4)) ^ (row & 7);
        bu[fn] = *(const bf16x8*)((const char*)&Bs[cur][0] + row * 128 + g * 16);
        bv[fn] = *(const bf16x8*)((const char*)&Bs[cur][0] + (row + 64) * 128 + g * 16);
      }
#pragma unroll
      for (int fm = 0; fm < 4; ++fm)
#pragma unroll
        for (int fn = 0; fn < 2; ++fn) {
          accU[fm][fn] = __builtin_amdgcn_mfma_f32_16x16x32_bf16(af[fm], bu[fn], accU[fm][fn], 0, 0, 0);
          accV[fm][fn] = __builtin_amdgcn_mfma_f32_16x16x32_bf16(af[fm], bv[fn], accV[fm][fn], 0, 0, 0);
        }
    }
    __syncthreads();
    cur ^= 1;
  }
#undef STAGE01

  const int eb = ebase[e];
#pragma unroll
  for (int fm = 0; fm < 4; ++fm) {
#pragma unroll
    for (int j2 = 0; j2 < 4; ++j2) {
      int lrow = wm * 64 + fm * 16 + (lane >> 4) * 4 + j2;
      int gr = r0 + lrow;
      if (gr >= ce) continue;
      size_t base = (size_t)(eb + gr) * FDIM + nBase + wn * 32 + (lane & 15);
#pragma unroll
      for (int fn = 0; fn < 2; ++fn) {
        float u = accU[fm][fn][j2], v = accV[fm][fn][j2];
        float h = (u / (1.f + __expf(-u))) * v;
        H[base + fn * 16] = f2bf(h);
      }
    }
  }
}

// ======= GEMM2: Y += (H @ W2t) * wgt, 128x128, BK=64, 2-phase =======
// XCD swizzle: 640 blocks = 8 XCD x 80 tiles; each XCD owns ONE 128-col D-panel.
__global__ __launch_bounds__(256) void gemm2_k(
    const unsigned short* __restrict__ A,    // H [HROWS][F]
    const unsigned short* __restrict__ B,    // w2t [E][D][F]
    float* __restrict__ Oy,
    const float* __restrict__ wgts, const int* __restrict__ lists,
    const int* __restrict__ cnt, const int* __restrict__ ebase,
    const int* __restrict__ tileE, const int* __restrict__ tileR,
    const int* __restrict__ numTiles) {
  const int bid = blockIdx.x;
  const int tix = bid >> 3;
  if (tix >= *numTiles) return;
  const int e = tileE[tix], r0 = tileR[tix], ce = cnt[e];
  const int nBase = (bid & 7) * 128;
  const int t = threadIdx.x, wave = t >> 6, lane = t & 63;

  __shared__ __align__(16) unsigned short As[2][128 * 64];
  __shared__ __align__(16) unsigned short Bs[2][128 * 64];

  const int cgs = (t & 7) ^ ((t >> 3) & 7);
  size_t aOff[4], bOff[4];
#pragma unroll
  for (int is = 0; is < 4; ++is) {
    int row = is * 32 + (t >> 3);
    size_t arow = (size_t)(ebase[e] + r0 + row);
    aOff[is] = (arow * FDIM + (size_t)(cgs * 8)) * 2;
    bOff[is] = (((size_t)e * DDIM + nBase + row) * FDIM + (size_t)(cgs * 8)) * 2;
  }

  f32x4 acc[4][4];
#pragma unroll
  for (int i = 0; i < 4; ++i)
#pragma unroll
    for (int j = 0; j < 4; ++j) acc[i][j] = 0.0f;

  const int wm = wave >> 1, wn = wave & 1;

#define STAGE2(buf, k0)                                                               \
  {                                                                                   \
    _Pragma("unroll") for (int is = 0; is < 4; ++is) {                                \
      glds16((const char*)A + aOff[is] + (size_t)(k0) * 2,                            \
             (char*)&As[buf][0] + is * 4096 + wave * 1024);                           \
      glds16((const char*)B + bOff[is] + (size_t)(k0) * 2,                            \
             (char*)&Bs[buf][0] + is * 4096 + wave * 1024);                           \
    }                                                                                 \
  }

  STAGE2(0, 0);
  __syncthreads();
  int cur = 0;
  for (int ks = 0; ks < FDIM / 64; ++ks) {
    if (ks < FDIM / 64 - 1) STAGE2(cur ^ 1, (ks + 1) * 64);
#pragma unroll
    for (int kk = 0; kk < 2; ++kk) {
      bf16x8 af[4], bfr[4];
#pragma unroll
      for (int fm = 0; fm < 4; ++fm) {
        int row = wm * 64 + fm * 16 + (lane & 15);
        int g = (kk * 4 + (lane >> 4)) ^ (row & 7);
        af[fm] = *(const bf16x8*)((const char*)&As[cur][0] + row * 128 + g * 16);
      }
#pragma unroll
      for (int fn = 0; fn < 4; ++fn) {
        int row = wn * 64 + fn * 16 + (lane & 15);
        int g = (kk * 4 + (lane >> 4)) ^ (row & 7);
        bfr[fn] = *(const bf16x8*)((const char*)&Bs[cur][0] + row * 128 + g * 16);
      }
#pragma unroll
      for (int fm = 0; fm < 4; ++fm)
#pragma unroll
        for (int fn = 0; fn < 4; ++fn)
          acc[fm][fn] = __builtin_amdgcn_mfma_f32_16x16x32_bf16(af[fm], bfr[fn], acc[fm][fn], 0, 0, 0);
    }
    __syncthreads();
    cur ^= 1;
  }
#undef STAGE2

#pragma unroll
  for (int fm = 0; fm < 4; ++fm) {
#pragma unroll
    for (int j = 0; j < 4; ++j) {
      int lrow = wm * 64 + fm * 16 + (lane >> 4) * 4 + j;
      int gr = r0 + lrow;
      if (gr >= ce) continue;
      int tok = lists[e * T_TOK + gr];
      float wv = wgts[e * T_TOK + gr];
      float* yrow = Oy + (size_t)tok * DDIM + nBase + wn * 64 + (lane & 15);
#pragma unroll
      for (int fn = 0; fn < 4; ++fn) atomicAdd(yrow + fn * 16, acc[fm][fn][j] * wv);
    }
  }
}

extern "C" void kernel_launch(void* const* d_in, const int* in_sizes, int n_in,
                              void* d_out, int out_size, void* d_ws, size_t ws_size,
                              hipStream_t stream) {
  const float* x  = (const float*)d_in[0];
  const float* gw = (const float*)d_in[1];
  const float* w1 = (const float*)d_in[2];   // dict order: x, gate_w, w1, w3, w2
  const float* w3 = (const float*)d_in[3];
  const float* w2 = (const float*)d_in[4];
  float* y = (float*)d_out;
  float* logits = y + (size_t)T_TOK * DDIM;

  char* ws = (char*)d_ws;
  size_t o = 0;
  auto alloc = [&](size_t bytes) {
    char* p = ws + o;
    o = (o + bytes + 255) & ~(size_t)255;
    return p;
  };
  unsigned short* xb  = (unsigned short*)alloc((size_t)T_TOK * DDIM * 2);
  unsigned short* w1t = (unsigned short*)alloc((size_t)NEXP * FDIM * DDIM * 2);  // [E][F][D]
  unsigned short* w3t = (unsigned short*)alloc((size_t)NEXP * FDIM * DDIM * 2);  // [E][F][D]
  unsigned short* w2t = (unsigned short*)alloc((size_t)NEXP * DDIM * FDIM * 2);  // [E][D][F]
  unsigned short* hb  = (unsigned short*)alloc((size_t)HROWS * FDIM * 2);        // h slots
  int*   lists = (int*)alloc((size_t)NEXP * T_TOK * 4);
  float* wgts  = (float*)alloc((size_t)NEXP * T_TOK * 4);
  int* cnt      = (int*)alloc(64);
  int* ebase    = (int*)alloc(64);
  int* tileE    = (int*)alloc(MAXTILES * 4);
  int* tileR    = (int*)alloc(MAXTILES * 4);
  int* numTiles = (int*)alloc(64);

  zero_k<<<4096, 256, 0, stream>>>(y, cnt);
  transpose_all_k<<<dim3(1024, 1, 24), 256, 0, stream>>>(w1, w3, w2, w1t, w3t, w2t);
  router_k<<<T_TOK / 4, 256, 0, stream>>>(x, gw, logits, xb, cnt, lists, wgts);
  meta_k<<<1, 64, 0, stream>>>(cnt, ebase, tileE, tileR, numTiles);

  gemm01_k<<<8 * 8 * MAXTILES, 256, 0, stream>>>(
      xb, w1t, w3t, hb, lists, cnt, ebase, tileE, tileR, numTiles);
  gemm2_k<<<8 * MAXTILES, 256, 0, stream>>>(
      hb, w2t, y, wgts, lists, cnt, ebase, tileE, tileR, numTiles);
}